// Round 2
// baseline (5490.147 us; speedup 1.0000x reference)
//
#include <hip/hip_runtime.h>

#define H 256
#define NLAYERS 6
typedef unsigned int uint32;
typedef unsigned short u16;

__device__ __forceinline__ float bf2f(u16 h) {
    return __uint_as_float(((uint32)h) << 16);
}
__device__ __forceinline__ u16 f2bf(float f) {
    uint32 u = __float_as_uint(f);
    u = u + 0x7FFFu + ((u >> 16) & 1u);   // round-nearest-even
    return (u16)(u >> 16);
}

// ---------------- sort pipeline ----------------

__global__ __launch_bounds__(256)
void count_kernel(const int* __restrict__ dst, int* __restrict__ deg, int E) {
    int e = blockIdx.x * 256 + threadIdx.x;
    if (e < E) atomicAdd(&deg[dst[e]], 1);
}

__global__ __launch_bounds__(256)
void invd_kernel(const int* __restrict__ deg, float* __restrict__ invd, int N) {
    int n = blockIdx.x * 256 + threadIdx.x;
    if (n < N) invd[n] = 1.f / fmaxf((float)deg[n], 1.f);
}

__global__ __launch_bounds__(256)
void scan1_kernel(const int* __restrict__ deg, int* __restrict__ bsum, int N) {
    __shared__ int s[256];
    int t = threadIdx.x;
    int i = blockIdx.x * 256 + t;
    s[t] = (i < N) ? deg[i] : 0;
    __syncthreads();
    for (int off = 128; off; off >>= 1) {
        if (t < off) s[t] += s[t + off];
        __syncthreads();
    }
    if (t == 0) bsum[blockIdx.x] = s[0];
}

__global__ __launch_bounds__(512)
void scan2_kernel(int* __restrict__ bsum, int nb) {
    __shared__ int s[512];
    int t = threadIdx.x;
    int v = (t < nb) ? bsum[t] : 0;
    s[t] = v;
    __syncthreads();
    for (int off = 1; off < 512; off <<= 1) {
        int x = (t >= off) ? s[t - off] : 0;
        __syncthreads();
        s[t] += x;
        __syncthreads();
    }
    if (t < nb) bsum[t] = s[t] - v;  // exclusive
}

__global__ __launch_bounds__(256)
void scan3_kernel(const int* __restrict__ deg, const int* __restrict__ bsum,
                  int* __restrict__ rowptr, int N, int E) {
    __shared__ int s[256];
    int t = threadIdx.x;
    int i = blockIdx.x * 256 + t;
    int v = (i < N) ? deg[i] : 0;
    s[t] = v;
    __syncthreads();
    for (int off = 1; off < 256; off <<= 1) {
        int x = (t >= off) ? s[t - off] : 0;
        __syncthreads();
        s[t] += x;
        __syncthreads();
    }
    if (i < N) rowptr[i] = s[t] - v + bsum[blockIdx.x];
    if (i == 0) rowptr[N] = E;
}

__global__ __launch_bounds__(256)
void scatter_kernel(const int* __restrict__ src, const int* __restrict__ dst,
                    const float* __restrict__ w, const int* __restrict__ rowptr,
                    int* __restrict__ cursor, int* __restrict__ srcS,
                    float* __restrict__ wS, int E) {
    int e = blockIdx.x * 256 + threadIdx.x;
    if (e >= E) return;
    int d = dst[e];
    int p = rowptr[d] + atomicAdd(&cursor[d], 1);
    srcS[p] = src[e];
    wS[(size_t)p * 3 + 0] = w[(size_t)e * 3 + 0];
    wS[(size_t)p * 3 + 1] = w[(size_t)e * 3 + 1];
    wS[(size_t)p * 3 + 2] = w[(size_t)e * 3 + 2];
}

// ---------------- embedding gather ----------------

__global__ __launch_bounds__(256)
void emb_kernel(const int* __restrict__ gt, const float* __restrict__ emb,
                float* __restrict__ h, int N) {
    int n = blockIdx.x * 4 + (threadIdx.x >> 6);
    int lane = threadIdx.x & 63;
    if (n >= N) return;
    ((float4*)h)[(size_t)n * 64 + lane] = ((const float4*)emb)[(size_t)gt[n] * 64 + lane];
}

// ---------------- t = h @ W1a^T  (bf16 out, col-split 64x64 tiles) ----------------

__global__ __launch_bounds__(256)
void gemm_t_kernel(const float* __restrict__ A, const float* __restrict__ W,
                   u16* __restrict__ T, int M) {
    __shared__ float As[32][68];
    __shared__ float Ws[32][68];
    const int tid = threadIdx.x;
    const int m0 = blockIdx.x * 64;
    const int n0 = blockIdx.y * 64;
    const int tx = tid & 15, ty = tid >> 4;
    float acc[4][4] = {};

    for (int k0 = 0; k0 < 256; k0 += 32) {
        #pragma unroll
        for (int i = 0; i < 8; ++i) {
            int e = i * 256 + tid;
            int k = e & 31, m = e >> 5;
            int row = m0 + m;
            As[k][m] = (row < M) ? A[(size_t)row * H + k0 + k] : 0.f;
            Ws[k][m] = W[(size_t)(n0 + m) * 259 + k0 + k];
        }
        __syncthreads();
        #pragma unroll
        for (int k = 0; k < 32; ++k) {
            float4 a4 = *(const float4*)&As[k][ty * 4];
            float4 b4 = *(const float4*)&Ws[k][tx * 4];
            float a_[4] = {a4.x, a4.y, a4.z, a4.w};
            float b_[4] = {b4.x, b4.y, b4.z, b4.w};
            #pragma unroll
            for (int r = 0; r < 4; ++r)
                #pragma unroll
                for (int c = 0; c < 4; ++c)
                    acc[r][c] = fmaf(a_[r], b_[c], acc[r][c]);
        }
        __syncthreads();
    }
    #pragma unroll
    for (int r = 0; r < 4; ++r) {
        int row = m0 + ty * 4 + r;
        if (row >= M) continue;
        ushort4 o;
        o.x = f2bf(acc[r][0]); o.y = f2bf(acc[r][1]);
        o.z = f2bf(acc[r][2]); o.w = f2bf(acc[r][3]);
        *(ushort4*)&T[(size_t)row * H + n0 + tx * 4] = o;
    }
}

// ---------------- edge aggregation: one wave per dst node, sorted edges ----------------

__global__ __launch_bounds__(256)
void edge_agg_kernel(const int* __restrict__ rowptr, const int* __restrict__ srcS,
                     const float* __restrict__ wS, const u16* __restrict__ T,
                     const float* __restrict__ W1l, const float* __restrict__ invd,
                     u16* __restrict__ hN, int N) {
    int n = blockIdx.x * 4 + (threadIdx.x >> 6);
    int lane = threadIdx.x & 63;
    if (n >= N) return;
    int col0 = lane * 4;
    float c0[4], c1[4], c2[4];
    #pragma unroll
    for (int q = 0; q < 4; ++q) {
        const float* wp = W1l + (size_t)(col0 + q) * 259 + 256;
        c0[q] = wp[0]; c1[q] = wp[1]; c2[q] = wp[2];
    }
    float acc[4] = {0.f, 0.f, 0.f, 0.f};
    int e0 = rowptr[n], e1 = rowptr[n + 1];
    for (int e = e0; e < e1; ++e) {
        int s = srcS[e];
        float w0 = wS[(size_t)e * 3 + 0];
        float w1 = wS[(size_t)e * 3 + 1];
        float w2 = wS[(size_t)e * 3 + 2];
        ushort4 tv = *(const ushort4*)&T[(size_t)s * H + col0];
        float v_[4] = {bf2f(tv.x), bf2f(tv.y), bf2f(tv.z), bf2f(tv.w)};
        #pragma unroll
        for (int q = 0; q < 4; ++q) {
            float x = v_[q] + w0 * c0[q] + w1 * c1[q] + w2 * c2[q];
            acc[q] += (x > 0.f) ? x : 0.01f * x;
        }
    }
    float sc = invd[n];
    ushort4 o;
    o.x = f2bf(acc[0] * sc); o.y = f2bf(acc[1] * sc);
    o.z = f2bf(acc[2] * sc); o.w = f2bf(acc[3] * sc);
    *(ushort4*)&hN[(size_t)n * H + col0] = o;
}

// ---------------- full-row GEMM (64x256 per block), relu+bias, in-place-safe ----------------
// C[row] = relu( [A fp32 (K=256) | A2 bf16 (K=256 if KTOT=512)] @ W^T + bias ), ldw = KTOT

template<int KTOT>
__global__ __launch_bounds__(256, 2)
void gemm_fr_kernel(const float* __restrict__ A, const u16* __restrict__ A2,
                    const float* __restrict__ W, const float* __restrict__ bias,
                    float* __restrict__ C, int M) {
    __shared__ float As[32][68];
    __shared__ float Ws2[32][260];
    const int tid = threadIdx.x;
    const int m0 = blockIdx.x * 64;
    const int tx = tid & 15, ty = tid >> 4;
    float acc[4][4][4] = {};

    for (int k0 = 0; k0 < KTOT; k0 += 32) {
        #pragma unroll
        for (int i = 0; i < 8; ++i) {
            int e = i * 256 + tid;
            int k = e & 31, m = e >> 5;
            int row = m0 + m;
            float v = 0.f;
            if (row < M) {
                if (KTOT == 256 || k0 < 256) v = A[(size_t)row * H + k0 + k];
                else v = bf2f(A2[(size_t)row * H + (k0 - 256) + k]);
            }
            As[k][m] = v;
        }
        #pragma unroll
        for (int i = 0; i < 32; ++i) {
            int e = i * 256 + tid;
            int k = e & 31, c = e >> 5;
            Ws2[k][c] = W[(size_t)c * KTOT + k0 + k];
        }
        __syncthreads();
        #pragma unroll
        for (int k = 0; k < 32; ++k) {
            float4 a4 = *(const float4*)&As[k][ty * 4];
            float a_[4] = {a4.x, a4.y, a4.z, a4.w};
            #pragma unroll
            for (int c4 = 0; c4 < 4; ++c4) {
                float4 b4 = *(const float4*)&Ws2[k][tx * 4 + 64 * c4];
                float b_[4] = {b4.x, b4.y, b4.z, b4.w};
                #pragma unroll
                for (int r = 0; r < 4; ++r)
                    #pragma unroll
                    for (int q = 0; q < 4; ++q)
                        acc[r][c4][q] = fmaf(a_[r], b_[q], acc[r][c4][q]);
            }
        }
        __syncthreads();
    }

    float bv[4][4];
    #pragma unroll
    for (int c4 = 0; c4 < 4; ++c4) {
        float4 b4 = *(const float4*)&bias[tx * 4 + 64 * c4];
        bv[c4][0] = b4.x; bv[c4][1] = b4.y; bv[c4][2] = b4.z; bv[c4][3] = b4.w;
    }
    #pragma unroll
    for (int r = 0; r < 4; ++r) {
        int row = m0 + ty * 4 + r;
        if (row >= M) continue;
        #pragma unroll
        for (int c4 = 0; c4 < 4; ++c4) {
            float4 o;
            o.x = fmaxf(acc[r][c4][0] + bv[c4][0], 0.f);
            o.y = fmaxf(acc[r][c4][1] + bv[c4][1], 0.f);
            o.z = fmaxf(acc[r][c4][2] + bv[c4][2], 0.f);
            o.w = fmaxf(acc[r][c4][3] + bv[c4][3], 0.f);
            *(float4*)&C[(size_t)row * H + tx * 4 + 64 * c4] = o;
        }
    }
}

// ---------------- head: out = x @ Wh2^T + bh2 ----------------

__global__ __launch_bounds__(256)
void head_out_kernel(const float* __restrict__ x, const float* __restrict__ wh2,
                     const float* __restrict__ bh2, float* __restrict__ out, int N) {
    int n = blockIdx.x * 4 + (threadIdx.x >> 6);
    int lane = threadIdx.x & 63;
    if (n >= N) return;
    float4 xv = ((const float4*)(x + (size_t)n * H))[lane];
    float4 wv = ((const float4*)wh2)[lane];
    float sum = xv.x * wv.x + xv.y * wv.y + xv.z * wv.z + xv.w * wv.w;
    #pragma unroll
    for (int off = 32; off; off >>= 1) sum += __shfl_xor(sum, off);
    if (lane == 0) out[n] = sum + bh2[0];
}

// ---------------- launch ----------------

extern "C" void kernel_launch(void* const* d_in, const int* in_sizes, int n_in,
                              void* d_out, int out_size, void* d_ws, size_t ws_size,
                              hipStream_t stream) {
    const int*   gate_type = (const int*)d_in[0];
    const int*   src  = (const int*)d_in[1];
    const int*   dst  = (const int*)d_in[2];
    const float* w    = (const float*)d_in[3];
    const float* emb  = (const float*)d_in[4];
    const float* W1   = (const float*)d_in[5];
    const float* W2   = (const float*)d_in[6];
    const float* b2   = (const float*)d_in[7];
    const float* Wh1  = (const float*)d_in[8];
    const float* bh1  = (const float*)d_in[9];
    const float* Wh2  = (const float*)d_in[10];
    const float* bh2  = (const float*)d_in[11];
    float* out = (float*)d_out;

    const int N = in_sizes[0];
    const int E = in_sizes[1];

    char* p = (char*)d_ws;
    auto alloc = [&](size_t bytes) -> char* {
        char* r = p;
        p += (bytes + 255) & ~(size_t)255;
        return r;
    };
    float* hBuf  = (float*)alloc((size_t)N * H * 4);   // 102.4 MB
    u16*   tBuf  = (u16*)  alloc((size_t)N * H * 2);   //  51.2 MB
    u16*   hNBuf = (u16*)  alloc((size_t)N * H * 2);   //  51.2 MB
    int*   srcS  = (int*)  alloc((size_t)E * 4);       //   3.2 MB
    float* wS    = (float*)alloc((size_t)E * 3 * 4);   //   9.6 MB
    int*   rowptr= (int*)  alloc((size_t)(N + 1) * 4);
    int*   cursor= (int*)  alloc((size_t)N * 4);
    int*   bsum  = (int*)  alloc(4096);
    float* invd  = (float*)alloc((size_t)N * 4);

    const int nb1 = (N + 255) / 256;

    // counting sort of edges by dst + inv_deg
    hipMemsetAsync(cursor, 0, (size_t)N * 4, stream);
    count_kernel<<<(E + 255) / 256, 256, 0, stream>>>(dst, cursor, E);
    invd_kernel<<<nb1, 256, 0, stream>>>(cursor, invd, N);
    scan1_kernel<<<nb1, 256, 0, stream>>>(cursor, bsum, N);
    scan2_kernel<<<1, 512, 0, stream>>>(bsum, nb1);
    scan3_kernel<<<nb1, 256, 0, stream>>>(cursor, bsum, rowptr, N, E);
    hipMemsetAsync(cursor, 0, (size_t)N * 4, stream);
    scatter_kernel<<<(E + 255) / 256, 256, 0, stream>>>(src, dst, w, rowptr, cursor, srcS, wS, E);

    // h = emb[gate_type]
    emb_kernel<<<(N + 3) / 4, 256, 0, stream>>>(gate_type, emb, hBuf, N);

    const int gm = (N + 63) / 64;
    for (int l = 0; l < NLAYERS; ++l) {
        const float* W1l = W1 + (size_t)l * 256 * 259;
        gemm_t_kernel<<<dim3(gm, 4), 256, 0, stream>>>(hBuf, W1l, tBuf, N);
        edge_agg_kernel<<<(N + 3) / 4, 256, 0, stream>>>(rowptr, srcS, wS, tBuf, W1l, invd, hNBuf, N);
        gemm_fr_kernel<512><<<gm, 256, 0, stream>>>(hBuf, hNBuf,
            W2 + (size_t)l * 256 * 512, b2 + (size_t)l * 256, hBuf, N);
    }
    // head
    gemm_fr_kernel<256><<<gm, 256, 0, stream>>>(hBuf, nullptr, Wh1, bh1, hBuf, N);
    head_out_kernel<<<(N + 3) / 4, 256, 0, stream>>>(hBuf, Wh2, bh2, out, N);
}

// Round 3
// 2208.426 us; speedup vs baseline: 2.4860x; 2.4860x over previous
//
#include <hip/hip_runtime.h>

#define H 256
#define NLAYERS 6
typedef unsigned int uint32;
typedef unsigned short u16;

typedef __bf16 bf16;
typedef bf16 bf16x8 __attribute__((ext_vector_type(8)));
typedef float f32x4 __attribute__((ext_vector_type(4)));

__device__ __forceinline__ float bf2f(u16 h) {
    return __uint_as_float(((uint32)h) << 16);
}
__device__ __forceinline__ u16 f2bf(float f) {
    uint32 u = __float_as_uint(f);
    u = u + 0x7FFFu + ((u >> 16) & 1u);   // round-nearest-even
    return (u16)(u >> 16);
}

__device__ __forceinline__ void glds16(const void* src, const char* ldsdst) {
    __builtin_amdgcn_global_load_lds(
        (const __attribute__((address_space(1))) void*)src,
        (__attribute__((address_space(3))) void*)ldsdst, 16, 0, 0);
}

// ---------------- sort pipeline ----------------

__global__ __launch_bounds__(256)
void count_kernel(const int* __restrict__ dst, int* __restrict__ deg, int E) {
    int e = blockIdx.x * 256 + threadIdx.x;
    if (e < E) atomicAdd(&deg[dst[e]], 1);
}

__global__ __launch_bounds__(256)
void invd_kernel(const int* __restrict__ deg, float* __restrict__ invd, int N) {
    int n = blockIdx.x * 256 + threadIdx.x;
    if (n < N) invd[n] = 1.f / fmaxf((float)deg[n], 1.f);
}

__global__ __launch_bounds__(256)
void scan1_kernel(const int* __restrict__ deg, int* __restrict__ bsum, int N) {
    __shared__ int s[256];
    int t = threadIdx.x;
    int i = blockIdx.x * 256 + t;
    s[t] = (i < N) ? deg[i] : 0;
    __syncthreads();
    for (int off = 128; off; off >>= 1) {
        if (t < off) s[t] += s[t + off];
        __syncthreads();
    }
    if (t == 0) bsum[blockIdx.x] = s[0];
}

__global__ __launch_bounds__(512)
void scan2_kernel(int* __restrict__ bsum, int nb) {
    __shared__ int s[512];
    int t = threadIdx.x;
    int v = (t < nb) ? bsum[t] : 0;
    s[t] = v;
    __syncthreads();
    for (int off = 1; off < 512; off <<= 1) {
        int x = (t >= off) ? s[t - off] : 0;
        __syncthreads();
        s[t] += x;
        __syncthreads();
    }
    if (t < nb) bsum[t] = s[t] - v;  // exclusive
}

__global__ __launch_bounds__(256)
void scan3_kernel(const int* __restrict__ deg, const int* __restrict__ bsum,
                  int* __restrict__ rowptr, int N, int E) {
    __shared__ int s[256];
    int t = threadIdx.x;
    int i = blockIdx.x * 256 + t;
    int v = (i < N) ? deg[i] : 0;
    s[t] = v;
    __syncthreads();
    for (int off = 1; off < 256; off <<= 1) {
        int x = (t >= off) ? s[t - off] : 0;
        __syncthreads();
        s[t] += x;
        __syncthreads();
    }
    if (i < N) rowptr[i] = s[t] - v + bsum[blockIdx.x];
    if (i == 0) rowptr[N] = E;
}

__global__ __launch_bounds__(256)
void scatter_kernel(const int* __restrict__ src, const int* __restrict__ dst,
                    const float* __restrict__ w, const int* __restrict__ rowptr,
                    int* __restrict__ cursor, int* __restrict__ srcS,
                    float* __restrict__ wS, int E) {
    int e = blockIdx.x * 256 + threadIdx.x;
    if (e >= E) return;
    int d = dst[e];
    int p = rowptr[d] + atomicAdd(&cursor[d], 1);
    srcS[p] = src[e];
    wS[(size_t)p * 3 + 0] = w[(size_t)e * 3 + 0];
    wS[(size_t)p * 3 + 1] = w[(size_t)e * 3 + 1];
    wS[(size_t)p * 3 + 2] = w[(size_t)e * 3 + 2];
}

// ---------------- weight split (hi/lo bf16) ----------------
// W1: [6][256][259] -> take first 256 cols -> [6][256][256]
// W2: [6][256][512] contiguous ; Wh1: [256][256] contiguous

__global__ __launch_bounds__(256)
void wsplit_kernel(const float* __restrict__ W1, const float* __restrict__ W2,
                   const float* __restrict__ Wh1,
                   u16* __restrict__ W1hi, u16* __restrict__ W1lo,
                   u16* __restrict__ W2hi, u16* __restrict__ W2lo,
                   u16* __restrict__ Wh1hi, u16* __restrict__ Wh1lo)
{
    int i = blockIdx.x * 256 + threadIdx.x;
    float v; u16* ph; u16* pl; int o;
    if (i < 393216) {                 // 6*256*256
        int l = i >> 16, rem = i & 65535, r = rem >> 8, k = rem & 255;
        v = W1[(size_t)l * 66304 + (size_t)r * 259 + k];   // 256*259 = 66304
        ph = W1hi; pl = W1lo; o = i;
    } else if (i < 1179648) {         // + 6*256*512
        int j = i - 393216;
        v = W2[j];
        ph = W2hi; pl = W2lo; o = j;
    } else if (i < 1245184) {         // + 256*256
        int j = i - 1179648;
        v = Wh1[j];
        ph = Wh1hi; pl = Wh1lo; o = j;
    } else return;
    u16 hi = f2bf(v);
    ph[o] = hi;
    pl[o] = f2bf(v - bf2f(hi));
}

// ---------------- embedding gather + split ----------------

__global__ __launch_bounds__(256)
void emb_split_kernel(const int* __restrict__ gt, const float* __restrict__ emb,
                      u16* __restrict__ hHi, u16* __restrict__ hLo, int N) {
    size_t idx = (size_t)blockIdx.x * 256 + threadIdx.x;
    if (idx >= (size_t)N * 256) return;
    int n = (int)(idx >> 8), c = (int)(idx & 255);
    float v = emb[(size_t)gt[n] * 256 + c];
    u16 hi = f2bf(v);
    hHi[idx] = hi;
    hLo[idx] = f2bf(v - bf2f(hi));
}

// ---------------- split-bf16 MFMA GEMM ----------------
// C[M x 256] = act( Acat[M x KTOT] @ W^T + bias )
// A (k<256): hi/lo bf16 pair, 3 products. A2 (k>=256, KTOT=512): single bf16, 2 products.
// W: hi/lo bf16 [256][KTOT] row-major.
// BM=64, BN=256 (full width -> in-place safe), BK=32, 4 waves x (64 rows x 64 cols).

#define LDS_AHI 0
#define LDS_ALO 4096
#define LDS_WHI 8192
#define LDS_WLO 24576

template<bool MAIN>
__device__ __forceinline__ void do_compute(const char* lds, const int* aoff,
                                           const int* woff, f32x4 (&acc)[4][4]) {
    bf16x8 ah[4], al[4];
    #pragma unroll
    for (int mi = 0; mi < 4; ++mi) {
        ah[mi] = *(const bf16x8*)(lds + LDS_AHI + aoff[mi]);
        if (MAIN) al[mi] = *(const bf16x8*)(lds + LDS_ALO + aoff[mi]);
    }
    #pragma unroll
    for (int nj = 0; nj < 4; ++nj) {
        bf16x8 wh = *(const bf16x8*)(lds + LDS_WHI + woff[nj]);
        bf16x8 wl = *(const bf16x8*)(lds + LDS_WLO + woff[nj]);
        #pragma unroll
        for (int mi = 0; mi < 4; ++mi) {
            acc[mi][nj] = __builtin_amdgcn_mfma_f32_16x16x32_bf16(ah[mi], wh, acc[mi][nj], 0, 0, 0);
            acc[mi][nj] = __builtin_amdgcn_mfma_f32_16x16x32_bf16(ah[mi], wl, acc[mi][nj], 0, 0, 0);
            if (MAIN)
                acc[mi][nj] = __builtin_amdgcn_mfma_f32_16x16x32_bf16(al[mi], wh, acc[mi][nj], 0, 0, 0);
        }
    }
}

template<int KTOT, bool BIASRELU, bool WLO>
__global__ __launch_bounds__(256)
void mfma_gemm_kernel(const u16* __restrict__ Ahi_, const u16* __restrict__ Alo_,
                      const u16* __restrict__ A2_,
                      const u16* __restrict__ Whi_, const u16* __restrict__ Wlo_,
                      const float* __restrict__ bias,
                      u16* __restrict__ Chi, u16* __restrict__ Clo, int M)
{
    __shared__ __align__(128) char lds[40960];
    const int tid = threadIdx.x;
    const int wv = tid >> 6;
    const int lane = tid & 63;
    const int m0 = blockIdx.x * 64;
    const int lrow = lane & 15, koct = lane >> 4;

    // fragment LDS byte offsets (fixed across k-steps; XOR-swizzled)
    int aoff[4], woff[4];
    #pragma unroll
    for (int mi = 0; mi < 4; ++mi) {
        int r = mi * 16 + lrow;
        aoff[mi] = r * 64 + ((koct ^ (r & 3)) << 4);
    }
    #pragma unroll
    for (int nj = 0; nj < 4; ++nj) {
        int r = wv * 64 + nj * 16 + lrow;
        woff[nj] = r * 64 + ((koct ^ (r & 3)) << 4);
    }

    // staging source precompute (pre-swizzled global source, linear LDS dest)
    const int arow = tid >> 2;
    const int acs = (tid & 3) ^ (arow & 3);
    const long agrow = (long)((m0 + arow < M) ? (m0 + arow) : (M - 1));
    const char* Asrc_hi = (const char*)Ahi_ + agrow * 512 + acs * 16;
    const char* Asrc_lo = (const char*)Alo_ + agrow * 512 + acs * 16;
    const char* Asrc_2  = (const char*)A2_  + agrow * 512 + acs * 16;

    f32x4 acc[4][4] = {};

    for (int k0 = 0; k0 < 256; k0 += 32) {
        glds16(Asrc_hi + k0 * 2, lds + LDS_AHI + wv * 1024);
        glds16(Asrc_lo + k0 * 2, lds + LDS_ALO + wv * 1024);
        #pragma unroll
        for (int rr = 0; rr < 4; ++rr) {
            int f = rr * 256 + tid;
            int wr = f >> 2;
            int wcs = (f & 3) ^ (wr & 3);
            glds16((const char*)Whi_ + (long)wr * (KTOT * 2) + k0 * 2 + wcs * 16,
                   lds + LDS_WHI + rr * 4096 + wv * 1024);
            glds16((const char*)Wlo_ + (long)wr * (KTOT * 2) + k0 * 2 + wcs * 16,
                   lds + LDS_WLO + rr * 4096 + wv * 1024);
        }
        __syncthreads();
        do_compute<true>(lds, aoff, woff, acc);
        __syncthreads();
    }
    if (KTOT > 256) {
        for (int k0 = 256; k0 < KTOT; k0 += 32) {
            glds16(Asrc_2 + (k0 - 256) * 2, lds + LDS_AHI + wv * 1024);
            #pragma unroll
            for (int rr = 0; rr < 4; ++rr) {
                int f = rr * 256 + tid;
                int wr = f >> 2;
                int wcs = (f & 3) ^ (wr & 3);
                glds16((const char*)Whi_ + (long)wr * (KTOT * 2) + k0 * 2 + wcs * 16,
                       lds + LDS_WHI + rr * 4096 + wv * 1024);
                glds16((const char*)Wlo_ + (long)wr * (KTOT * 2) + k0 * 2 + wcs * 16,
                       lds + LDS_WLO + rr * 4096 + wv * 1024);
            }
            __syncthreads();
            do_compute<false>(lds, aoff, woff, acc);
            __syncthreads();
        }
    }

    float bv[4] = {0.f, 0.f, 0.f, 0.f};
    if (BIASRELU) {
        #pragma unroll
        for (int nj = 0; nj < 4; ++nj) bv[nj] = bias[wv * 64 + nj * 16 + lrow];
    }
    #pragma unroll
    for (int mi = 0; mi < 4; ++mi) {
        #pragma unroll
        for (int r = 0; r < 4; ++r) {
            int row = m0 + mi * 16 + koct * 4 + r;
            if (row >= M) continue;
            #pragma unroll
            for (int nj = 0; nj < 4; ++nj) {
                float v = acc[mi][nj][r];
                if (BIASRELU) v = fmaxf(v + bv[nj], 0.f);
                size_t o = (size_t)row * 256 + wv * 64 + nj * 16 + lrow;
                u16 hi = f2bf(v);
                Chi[o] = hi;
                if (WLO) Clo[o] = f2bf(v - bf2f(hi));
            }
        }
    }
}

// ---------------- edge aggregation: one wave per dst node, sorted edges ----------------

__global__ __launch_bounds__(256)
void edge_agg_kernel(const int* __restrict__ rowptr, const int* __restrict__ srcS,
                     const float* __restrict__ wS, const u16* __restrict__ T,
                     const float* __restrict__ W1l, const float* __restrict__ invd,
                     u16* __restrict__ hN, int N) {
    int n = blockIdx.x * 4 + (threadIdx.x >> 6);
    int lane = threadIdx.x & 63;
    if (n >= N) return;
    int col0 = lane * 4;
    float c0[4], c1[4], c2[4];
    #pragma unroll
    for (int q = 0; q < 4; ++q) {
        const float* wp = W1l + (size_t)(col0 + q) * 259 + 256;
        c0[q] = wp[0]; c1[q] = wp[1]; c2[q] = wp[2];
    }
    float acc[4] = {0.f, 0.f, 0.f, 0.f};
    int e0 = rowptr[n], e1 = rowptr[n + 1];
    for (int e = e0; e < e1; ++e) {
        int s = srcS[e];
        float w0 = wS[(size_t)e * 3 + 0];
        float w1 = wS[(size_t)e * 3 + 1];
        float w2 = wS[(size_t)e * 3 + 2];
        ushort4 tv = *(const ushort4*)&T[(size_t)s * H + col0];
        float v_[4] = {bf2f(tv.x), bf2f(tv.y), bf2f(tv.z), bf2f(tv.w)};
        #pragma unroll
        for (int q = 0; q < 4; ++q) {
            float x = v_[q] + w0 * c0[q] + w1 * c1[q] + w2 * c2[q];
            acc[q] += (x > 0.f) ? x : 0.01f * x;
        }
    }
    float sc = invd[n];
    ushort4 o;
    o.x = f2bf(acc[0] * sc); o.y = f2bf(acc[1] * sc);
    o.z = f2bf(acc[2] * sc); o.w = f2bf(acc[3] * sc);
    *(ushort4*)&hN[(size_t)n * H + col0] = o;
}

// ---------------- head: out = x @ Wh2^T + bh2 ----------------

__global__ __launch_bounds__(256)
void head_out_kernel(const u16* __restrict__ xhi, const u16* __restrict__ xlo,
                     const float* __restrict__ wh2,
                     const float* __restrict__ bh2, float* __restrict__ out, int N) {
    int n = blockIdx.x * 4 + (threadIdx.x >> 6);
    int lane = threadIdx.x & 63;
    if (n >= N) return;
    ushort4 hv = ((const ushort4*)(xhi + (size_t)n * H))[lane];
    ushort4 lv = ((const ushort4*)(xlo + (size_t)n * H))[lane];
    float4 wv = ((const float4*)wh2)[lane];
    float x0 = bf2f(hv.x) + bf2f(lv.x);
    float x1 = bf2f(hv.y) + bf2f(lv.y);
    float x2 = bf2f(hv.z) + bf2f(lv.z);
    float x3 = bf2f(hv.w) + bf2f(lv.w);
    float sum = x0 * wv.x + x1 * wv.y + x2 * wv.z + x3 * wv.w;
    #pragma unroll
    for (int off = 32; off; off >>= 1) sum += __shfl_xor(sum, off);
    if (lane == 0) out[n] = sum + bh2[0];
}

// ---------------- launch ----------------

extern "C" void kernel_launch(void* const* d_in, const int* in_sizes, int n_in,
                              void* d_out, int out_size, void* d_ws, size_t ws_size,
                              hipStream_t stream) {
    const int*   gate_type = (const int*)d_in[0];
    const int*   src  = (const int*)d_in[1];
    const int*   dst  = (const int*)d_in[2];
    const float* w    = (const float*)d_in[3];
    const float* emb  = (const float*)d_in[4];
    const float* W1   = (const float*)d_in[5];
    const float* W2   = (const float*)d_in[6];
    const float* b2   = (const float*)d_in[7];
    const float* Wh1  = (const float*)d_in[8];
    const float* bh1  = (const float*)d_in[9];
    const float* Wh2  = (const float*)d_in[10];
    const float* bh2  = (const float*)d_in[11];
    float* out = (float*)d_out;

    const int N = in_sizes[0];
    const int E = in_sizes[1];

    char* p = (char*)d_ws;
    auto alloc = [&](size_t bytes) -> char* {
        char* r = p;
        p += (bytes + 1023) & ~(size_t)1023;
        return r;
    };
    u16*   hHi   = (u16*)  alloc((size_t)N * H * 2);   // 51.2 MB
    u16*   hLo   = (u16*)  alloc((size_t)N * H * 2);   // 51.2 MB
    u16*   tBuf  = (u16*)  alloc((size_t)N * H * 2);   // 51.2 MB
    u16*   hNBuf = (u16*)  alloc((size_t)N * H * 2);   // 51.2 MB
    int*   srcS  = (int*)  alloc((size_t)E * 4);       //  3.2 MB
    float* wS    = (float*)alloc((size_t)E * 3 * 4);   //  9.6 MB
    int*   rowptr= (int*)  alloc((size_t)(N + 1) * 4);
    int*   cursor= (int*)  alloc((size_t)N * 4);
    int*   bsum  = (int*)  alloc(4096);
    float* invd  = (float*)alloc((size_t)N * 4);
    u16*   W1hi  = (u16*)  alloc(6u * 256 * 256 * 2);
    u16*   W1lo  = (u16*)  alloc(6u * 256 * 256 * 2);
    u16*   W2hi  = (u16*)  alloc(6u * 256 * 512 * 2);
    u16*   W2lo  = (u16*)  alloc(6u * 256 * 512 * 2);
    u16*   Wh1hi = (u16*)  alloc(256u * 256 * 2);
    u16*   Wh1lo = (u16*)  alloc(256u * 256 * 2);

    const int nb1 = (N + 255) / 256;

    // counting sort of edges by dst + inv_deg
    hipMemsetAsync(cursor, 0, (size_t)N * 4, stream);
    count_kernel<<<(E + 255) / 256, 256, 0, stream>>>(dst, cursor, E);
    invd_kernel<<<nb1, 256, 0, stream>>>(cursor, invd, N);
    scan1_kernel<<<nb1, 256, 0, stream>>>(cursor, bsum, N);
    scan2_kernel<<<1, 512, 0, stream>>>(bsum, nb1);
    scan3_kernel<<<nb1, 256, 0, stream>>>(cursor, bsum, rowptr, N, E);
    hipMemsetAsync(cursor, 0, (size_t)N * 4, stream);
    scatter_kernel<<<(E + 255) / 256, 256, 0, stream>>>(src, dst, w, rowptr, cursor, srcS, wS, E);

    // weight split + embedding
    wsplit_kernel<<<4864, 256, 0, stream>>>(W1, W2, Wh1, W1hi, W1lo, W2hi, W2lo, Wh1hi, Wh1lo);
    emb_split_kernel<<<N, 256, 0, stream>>>(gate_type, emb, hHi, hLo, N);

    const int gm = (N + 63) / 64;
    for (int l = 0; l < NLAYERS; ++l) {
        const float* W1l = W1 + (size_t)l * 256 * 259;
        // t = h @ W1a^T  (bf16x3, out single bf16)
        mfma_gemm_kernel<256, false, false><<<gm, 256, 0, stream>>>(
            hHi, hLo, nullptr, W1hi + (size_t)l * 65536, W1lo + (size_t)l * 65536,
            nullptr, tBuf, nullptr, N);
        edge_agg_kernel<<<(N + 3) / 4, 256, 0, stream>>>(rowptr, srcS, wS, tBuf, W1l, invd, hNBuf, N);
        // h = relu([h, hN] @ W2^T + b2)  (in-place: BN=256 full-width blocks)
        mfma_gemm_kernel<512, true, true><<<gm, 256, 0, stream>>>(
            hHi, hLo, hNBuf, W2hi + (size_t)l * 131072, W2lo + (size_t)l * 131072,
            b2 + (size_t)l * 256, hHi, hLo, N);
    }
    // head
    mfma_gemm_kernel<256, true, true><<<gm, 256, 0, stream>>>(
        hHi, hLo, nullptr, Wh1hi, Wh1lo, bh1, hHi, hLo, N);
    head_out_kernel<<<(N + 3) / 4, 256, 0, stream>>>(hHi, hLo, Wh2, bh2, out, N);
}

// Round 4
// 1885.334 us; speedup vs baseline: 2.9120x; 1.1714x over previous
//
#include <hip/hip_runtime.h>

#define H 256
#define NLAYERS 6
typedef unsigned int uint32;
typedef unsigned short u16;

typedef __bf16 bf16;
typedef bf16 bf16x8 __attribute__((ext_vector_type(8)));
typedef float f32x4 __attribute__((ext_vector_type(4)));
typedef u16 u16x8 __attribute__((ext_vector_type(8)));

__device__ __forceinline__ float bf2f(u16 h) {
    return __uint_as_float(((uint32)h) << 16);
}
__device__ __forceinline__ u16 f2bf(float f) {
    uint32 u = __float_as_uint(f);
    u = u + 0x7FFFu + ((u >> 16) & 1u);   // round-nearest-even
    return (u16)(u >> 16);
}

__device__ __forceinline__ void glds16(const void* src, const char* ldsdst) {
    __builtin_amdgcn_global_load_lds(
        (const __attribute__((address_space(1))) void*)src,
        (__attribute__((address_space(3))) void*)ldsdst, 16, 0, 0);
}

// ---------------- sort pipeline ----------------

__global__ __launch_bounds__(256)
void count_kernel(const int* __restrict__ dst, int* __restrict__ deg, int E) {
    int e = blockIdx.x * 256 + threadIdx.x;
    if (e < E) atomicAdd(&deg[dst[e]], 1);
}

__global__ __launch_bounds__(256)
void invd_kernel(const int* __restrict__ deg, float* __restrict__ invd, int N) {
    int n = blockIdx.x * 256 + threadIdx.x;
    if (n < N) invd[n] = 1.f / fmaxf((float)deg[n], 1.f);
}

__global__ __launch_bounds__(256)
void scan1_kernel(const int* __restrict__ deg, int* __restrict__ bsum, int N) {
    __shared__ int s[256];
    int t = threadIdx.x;
    int i = blockIdx.x * 256 + t;
    s[t] = (i < N) ? deg[i] : 0;
    __syncthreads();
    for (int off = 128; off; off >>= 1) {
        if (t < off) s[t] += s[t + off];
        __syncthreads();
    }
    if (t == 0) bsum[blockIdx.x] = s[0];
}

__global__ __launch_bounds__(512)
void scan2_kernel(int* __restrict__ bsum, int nb) {
    __shared__ int s[512];
    int t = threadIdx.x;
    int v = (t < nb) ? bsum[t] : 0;
    s[t] = v;
    __syncthreads();
    for (int off = 1; off < 512; off <<= 1) {
        int x = (t >= off) ? s[t - off] : 0;
        __syncthreads();
        s[t] += x;
        __syncthreads();
    }
    if (t < nb) bsum[t] = s[t] - v;  // exclusive
}

__global__ __launch_bounds__(256)
void scan3_kernel(const int* __restrict__ deg, const int* __restrict__ bsum,
                  int* __restrict__ rowptr, int N, int E) {
    __shared__ int s[256];
    int t = threadIdx.x;
    int i = blockIdx.x * 256 + t;
    int v = (i < N) ? deg[i] : 0;
    s[t] = v;
    __syncthreads();
    for (int off = 1; off < 256; off <<= 1) {
        int x = (t >= off) ? s[t - off] : 0;
        __syncthreads();
        s[t] += x;
        __syncthreads();
    }
    if (i < N) rowptr[i] = s[t] - v + bsum[blockIdx.x];
    if (i == 0) rowptr[N] = E;
}

__global__ __launch_bounds__(256)
void scatter_kernel(const int* __restrict__ src, const int* __restrict__ dst,
                    const float* __restrict__ w, const int* __restrict__ rowptr,
                    int* __restrict__ cursor, int* __restrict__ srcS,
                    float* __restrict__ wS, int E) {
    int e = blockIdx.x * 256 + threadIdx.x;
    if (e >= E) return;
    int d = dst[e];
    int p = rowptr[d] + atomicAdd(&cursor[d], 1);
    srcS[p] = src[e];
    float4 wq;
    wq.x = w[(size_t)e * 3 + 0];
    wq.y = w[(size_t)e * 3 + 1];
    wq.z = w[(size_t)e * 3 + 2];
    wq.w = 0.f;
    *(float4*)&wS[(size_t)p * 4] = wq;
}

// ---------------- weight split (hi/lo bf16) ----------------

__global__ __launch_bounds__(256)
void wsplit_kernel(const float* __restrict__ W1, const float* __restrict__ W2,
                   const float* __restrict__ Wh1,
                   u16* __restrict__ W1hi, u16* __restrict__ W1lo,
                   u16* __restrict__ W2hi, u16* __restrict__ W2lo,
                   u16* __restrict__ Wh1hi, u16* __restrict__ Wh1lo)
{
    int i = blockIdx.x * 256 + threadIdx.x;
    float v; u16* ph; u16* pl; int o;
    if (i < 393216) {                 // 6*256*256
        int l = i >> 16, rem = i & 65535, r = rem >> 8, k = rem & 255;
        v = W1[(size_t)l * 66304 + (size_t)r * 259 + k];   // 256*259 = 66304
        ph = W1hi; pl = W1lo; o = i;
    } else if (i < 1179648) {         // + 6*256*512
        int j = i - 393216;
        v = W2[j];
        ph = W2hi; pl = W2lo; o = j;
    } else if (i < 1245184) {         // + 256*256
        int j = i - 1179648;
        v = Wh1[j];
        ph = Wh1hi; pl = Wh1lo; o = j;
    } else return;
    u16 hi = f2bf(v);
    ph[o] = hi;
    pl[o] = f2bf(v - bf2f(hi));
}

// extract edge-coefficient columns for ALL layers: cc[l][3][256]
__global__ void extract_kernel(const float* __restrict__ W1, float* __restrict__ ccAll)
{
    int l = blockIdx.x;
    int i = threadIdx.x;
    const float* W1l = W1 + (size_t)l * 66304;
    float* cc = ccAll + (size_t)l * 768;
    #pragma unroll
    for (int j = 0; j < 3; ++j)
        cc[j * 256 + i] = W1l[(size_t)i * 259 + 256 + j];
}

// ---------------- embedding gather + split ----------------

__global__ __launch_bounds__(256)
void emb_split_kernel(const int* __restrict__ gt, const float* __restrict__ emb,
                      u16* __restrict__ hHi, u16* __restrict__ hLo, int N) {
    size_t idx = (size_t)blockIdx.x * 256 + threadIdx.x;
    if (idx >= (size_t)N * 256) return;
    int n = (int)(idx >> 8), c = (int)(idx & 255);
    float v = emb[(size_t)gt[n] * 256 + c];
    u16 hi = f2bf(v);
    hHi[idx] = hi;
    hLo[idx] = f2bf(v - bf2f(hi));
}

// ---------------- split-bf16 MFMA GEMM ----------------
// C[M x 256] = act( Acat[M x KTOT] @ W^T + bias )
// Operand-swapped MFMA: D = mfma(W_frag, A_frag) so each lane holds 4
// CONSECUTIVE feature cols of one row -> ushort4 coalesced stores.
// BM=64, BN=256 (full width -> in-place safe), BK=32, 4 waves x (64 rows x 64 cols).

#define LDS_AHI 0
#define LDS_ALO 4096
#define LDS_WHI 8192
#define LDS_WLO 24576

template<bool MAIN>
__device__ __forceinline__ void do_compute(const char* lds, const int* aoff,
                                           const int* woff, f32x4 (&acc)[4][4]) {
    bf16x8 ah[4], al[4];
    #pragma unroll
    for (int mi = 0; mi < 4; ++mi) {
        ah[mi] = *(const bf16x8*)(lds + LDS_AHI + aoff[mi]);
        if (MAIN) al[mi] = *(const bf16x8*)(lds + LDS_ALO + aoff[mi]);
    }
    #pragma unroll
    for (int nj = 0; nj < 4; ++nj) {
        bf16x8 wh = *(const bf16x8*)(lds + LDS_WHI + woff[nj]);
        bf16x8 wl = *(const bf16x8*)(lds + LDS_WLO + woff[nj]);
        #pragma unroll
        for (int mi = 0; mi < 4; ++mi) {
            acc[mi][nj] = __builtin_amdgcn_mfma_f32_16x16x32_bf16(wh, ah[mi], acc[mi][nj], 0, 0, 0);
            acc[mi][nj] = __builtin_amdgcn_mfma_f32_16x16x32_bf16(wl, ah[mi], acc[mi][nj], 0, 0, 0);
            if (MAIN)
                acc[mi][nj] = __builtin_amdgcn_mfma_f32_16x16x32_bf16(wh, al[mi], acc[mi][nj], 0, 0, 0);
        }
    }
}

template<int KTOT, bool BIASRELU, bool WLO>
__global__ __launch_bounds__(256)
void mfma_gemm_kernel(const u16* __restrict__ Ahi_, const u16* __restrict__ Alo_,
                      const u16* __restrict__ A2_,
                      const u16* __restrict__ Whi_, const u16* __restrict__ Wlo_,
                      const float* __restrict__ bias,
                      u16* __restrict__ Chi, u16* __restrict__ Clo, int M)
{
    __shared__ __align__(128) char lds[40960];
    const int tid = threadIdx.x;
    const int wv = tid >> 6;
    const int lane = tid & 63;
    const int m0 = blockIdx.x * 64;
    const int lrow = lane & 15, koct = lane >> 4;

    // fragment LDS byte offsets (fixed across k-steps; XOR-swizzled)
    int aoff[4], woff[4];
    #pragma unroll
    for (int mi = 0; mi < 4; ++mi) {
        int r = mi * 16 + lrow;
        aoff[mi] = r * 64 + ((koct ^ (r & 3)) << 4);
    }
    #pragma unroll
    for (int nj = 0; nj < 4; ++nj) {
        int r = wv * 64 + nj * 16 + lrow;
        woff[nj] = r * 64 + ((koct ^ (r & 3)) << 4);
    }

    // staging source precompute (pre-swizzled global source, linear LDS dest)
    const int arow = tid >> 2;
    const int acs = (tid & 3) ^ (arow & 3);
    const long agrow = (long)((m0 + arow < M) ? (m0 + arow) : (M - 1));
    const char* Asrc_hi = (const char*)Ahi_ + agrow * 512 + acs * 16;
    const char* Asrc_lo = (const char*)Alo_ + agrow * 512 + acs * 16;
    const char* Asrc_2  = (const char*)A2_  + agrow * 512 + acs * 16;

    f32x4 acc[4][4] = {};

    for (int k0 = 0; k0 < 256; k0 += 32) {
        glds16(Asrc_hi + k0 * 2, lds + LDS_AHI + wv * 1024);
        glds16(Asrc_lo + k0 * 2, lds + LDS_ALO + wv * 1024);
        #pragma unroll
        for (int rr = 0; rr < 4; ++rr) {
            int f = rr * 256 + tid;
            int wr = f >> 2;
            int wcs = (f & 3) ^ (wr & 3);
            glds16((const char*)Whi_ + (long)wr * (KTOT * 2) + k0 * 2 + wcs * 16,
                   lds + LDS_WHI + rr * 4096 + wv * 1024);
            glds16((const char*)Wlo_ + (long)wr * (KTOT * 2) + k0 * 2 + wcs * 16,
                   lds + LDS_WLO + rr * 4096 + wv * 1024);
        }
        __syncthreads();
        do_compute<true>(lds, aoff, woff, acc);
        __syncthreads();
    }
    if (KTOT > 256) {
        for (int k0 = 256; k0 < KTOT; k0 += 32) {
            glds16(Asrc_2 + (k0 - 256) * 2, lds + LDS_AHI + wv * 1024);
            #pragma unroll
            for (int rr = 0; rr < 4; ++rr) {
                int f = rr * 256 + tid;
                int wr = f >> 2;
                int wcs = (f & 3) ^ (wr & 3);
                glds16((const char*)Whi_ + (long)wr * (KTOT * 2) + k0 * 2 + wcs * 16,
                       lds + LDS_WHI + rr * 4096 + wv * 1024);
                glds16((const char*)Wlo_ + (long)wr * (KTOT * 2) + k0 * 2 + wcs * 16,
                       lds + LDS_WLO + rr * 4096 + wv * 1024);
            }
            __syncthreads();
            do_compute<false>(lds, aoff, woff, acc);
            __syncthreads();
        }
    }

    // epilogue: lane holds rows (mi*16+lrow), cols wv*64 + nj*16 + koct*4 .. +4
    float4 bv[4];
    if (BIASRELU) {
        #pragma unroll
        for (int nj = 0; nj < 4; ++nj)
            bv[nj] = *(const float4*)&bias[wv * 64 + nj * 16 + koct * 4];
    }
    #pragma unroll
    for (int mi = 0; mi < 4; ++mi) {
        int row = m0 + mi * 16 + lrow;
        if (row >= M) continue;
        #pragma unroll
        for (int nj = 0; nj < 4; ++nj) {
            f32x4 v = acc[mi][nj];
            if (BIASRELU) {
                v[0] = fmaxf(v[0] + bv[nj].x, 0.f);
                v[1] = fmaxf(v[1] + bv[nj].y, 0.f);
                v[2] = fmaxf(v[2] + bv[nj].z, 0.f);
                v[3] = fmaxf(v[3] + bv[nj].w, 0.f);
            }
            size_t o = (size_t)row * 256 + wv * 64 + nj * 16 + koct * 4;
            ushort4 ohi;
            ohi.x = f2bf(v[0]); ohi.y = f2bf(v[1]);
            ohi.z = f2bf(v[2]); ohi.w = f2bf(v[3]);
            *(ushort4*)&Chi[o] = ohi;
            if (WLO) {
                ushort4 olo;
                olo.x = f2bf(v[0] - bf2f(ohi.x));
                olo.y = f2bf(v[1] - bf2f(ohi.y));
                olo.z = f2bf(v[2] - bf2f(ohi.z));
                olo.w = f2bf(v[3] - bf2f(ohi.w));
                *(ushort4*)&Clo[o] = olo;
            }
        }
    }
}

// ---------------- edge aggregation ----------------
// one wave per dst node; two 32-lane halves each cover all 256 cols (ushort8)
// and process alternate edges; x2 unroll -> 4 independent gathers in flight.

__global__ __launch_bounds__(256)
void edge_agg_kernel(const int* __restrict__ rowptr, const int* __restrict__ srcS,
                     const float* __restrict__ wS, const u16* __restrict__ T,
                     const float* __restrict__ cc, const float* __restrict__ invd,
                     u16* __restrict__ hN, int N) {
    int n = blockIdx.x * 4 + (threadIdx.x >> 6);
    int lane = threadIdx.x & 63;
    if (n >= N) return;
    const int half = lane >> 5;
    const int c32 = lane & 31;
    const int col0 = c32 * 8;

    float c0[8], c1[8], c2[8];
    #pragma unroll
    for (int j = 0; j < 3; ++j) {
        float4 lo4 = *(const float4*)&cc[j * 256 + col0];
        float4 hi4 = *(const float4*)&cc[j * 256 + col0 + 4];
        float* cj = (j == 0) ? c0 : (j == 1) ? c1 : c2;
        cj[0] = lo4.x; cj[1] = lo4.y; cj[2] = lo4.z; cj[3] = lo4.w;
        cj[4] = hi4.x; cj[5] = hi4.y; cj[6] = hi4.z; cj[7] = hi4.w;
    }

    float acc[8] = {};
    const int e0 = rowptr[n], e1 = rowptr[n + 1];
    int e = e0 + half;
    // unrolled: this half-wave handles edges e, e+2 per iteration
    for (; e + 2 < e1; e += 4) {
        int s0 = srcS[e];
        int s1 = srcS[e + 2];
        float4 wa = *(const float4*)&wS[(size_t)e * 4];
        float4 wb = *(const float4*)&wS[(size_t)(e + 2) * 4];
        u16x8 t0 = *(const u16x8*)&T[(size_t)s0 * 256 + col0];
        u16x8 t1 = *(const u16x8*)&T[(size_t)s1 * 256 + col0];
        #pragma unroll
        for (int q = 0; q < 8; ++q) {
            float x = fmaf(wa.x, c0[q], fmaf(wa.y, c1[q], fmaf(wa.z, c2[q], bf2f(t0[q]))));
            acc[q] += (x > 0.f) ? x : 0.01f * x;
            float y = fmaf(wb.x, c0[q], fmaf(wb.y, c1[q], fmaf(wb.z, c2[q], bf2f(t1[q]))));
            acc[q] += (y > 0.f) ? y : 0.01f * y;
        }
    }
    for (; e < e1; e += 2) {
        int s0 = srcS[e];
        float4 wa = *(const float4*)&wS[(size_t)e * 4];
        u16x8 t0 = *(const u16x8*)&T[(size_t)s0 * 256 + col0];
        #pragma unroll
        for (int q = 0; q < 8; ++q) {
            float x = fmaf(wa.x, c0[q], fmaf(wa.y, c1[q], fmaf(wa.z, c2[q], bf2f(t0[q]))));
            acc[q] += (x > 0.f) ? x : 0.01f * x;
        }
    }
    // combine the two halves (same cols)
    #pragma unroll
    for (int q = 0; q < 8; ++q) acc[q] += __shfl_xor(acc[q], 32);
    if (half == 0) {
        float sc = invd[n];
        u16x8 o;
        #pragma unroll
        for (int q = 0; q < 8; ++q) o[q] = f2bf(acc[q] * sc);
        *(u16x8*)&hN[(size_t)n * 256 + col0] = o;
    }
}

// ---------------- head: out = x @ Wh2^T + bh2 ----------------

__global__ __launch_bounds__(256)
void head_out_kernel(const u16* __restrict__ xhi, const u16* __restrict__ xlo,
                     const float* __restrict__ wh2,
                     const float* __restrict__ bh2, float* __restrict__ out, int N) {
    int n = blockIdx.x * 4 + (threadIdx.x >> 6);
    int lane = threadIdx.x & 63;
    if (n >= N) return;
    ushort4 hv = ((const ushort4*)(xhi + (size_t)n * H))[lane];
    ushort4 lv = ((const ushort4*)(xlo + (size_t)n * H))[lane];
    float4 wv = ((const float4*)wh2)[lane];
    float x0 = bf2f(hv.x) + bf2f(lv.x);
    float x1 = bf2f(hv.y) + bf2f(lv.y);
    float x2 = bf2f(hv.z) + bf2f(lv.z);
    float x3 = bf2f(hv.w) + bf2f(lv.w);
    float sum = x0 * wv.x + x1 * wv.y + x2 * wv.z + x3 * wv.w;
    #pragma unroll
    for (int off = 32; off; off >>= 1) sum += __shfl_xor(sum, off);
    if (lane == 0) out[n] = sum + bh2[0];
}

// ---------------- launch ----------------

extern "C" void kernel_launch(void* const* d_in, const int* in_sizes, int n_in,
                              void* d_out, int out_size, void* d_ws, size_t ws_size,
                              hipStream_t stream) {
    const int*   gate_type = (const int*)d_in[0];
    const int*   src  = (const int*)d_in[1];
    const int*   dst  = (const int*)d_in[2];
    const float* w    = (const float*)d_in[3];
    const float* emb  = (const float*)d_in[4];
    const float* W1   = (const float*)d_in[5];
    const float* W2   = (const float*)d_in[6];
    const float* b2   = (const float*)d_in[7];
    const float* Wh1  = (const float*)d_in[8];
    const float* bh1  = (const float*)d_in[9];
    const float* Wh2  = (const float*)d_in[10];
    const float* bh2  = (const float*)d_in[11];
    float* out = (float*)d_out;

    const int N = in_sizes[0];
    const int E = in_sizes[1];

    char* p = (char*)d_ws;
    auto alloc = [&](size_t bytes) -> char* {
        char* r = p;
        p += (bytes + 1023) & ~(size_t)1023;
        return r;
    };
    u16*   hHi   = (u16*)  alloc((size_t)N * H * 2);   // 51.2 MB
    u16*   hLo   = (u16*)  alloc((size_t)N * H * 2);   // 51.2 MB
    u16*   tBuf  = (u16*)  alloc((size_t)N * H * 2);   // 51.2 MB
    u16*   hNBuf = (u16*)  alloc((size_t)N * H * 2);   // 51.2 MB
    int*   srcS  = (int*)  alloc((size_t)E * 4);       //  3.2 MB
    float* wS    = (float*)alloc((size_t)E * 4 * 4);   // 12.8 MB
    int*   rowptr= (int*)  alloc((size_t)(N + 1) * 4);
    int*   cursor= (int*)  alloc((size_t)N * 4);
    int*   bsum  = (int*)  alloc(4096);
    float* invd  = (float*)alloc((size_t)N * 4);
    float* ccAll = (float*)alloc(6u * 768 * 4);
    u16*   W1hi  = (u16*)  alloc(6u * 256 * 256 * 2);
    u16*   W1lo  = (u16*)  alloc(6u * 256 * 256 * 2);
    u16*   W2hi  = (u16*)  alloc(6u * 256 * 512 * 2);
    u16*   W2lo  = (u16*)  alloc(6u * 256 * 512 * 2);
    u16*   Wh1hi = (u16*)  alloc(256u * 256 * 2);
    u16*   Wh1lo = (u16*)  alloc(256u * 256 * 2);

    const int nb1 = (N + 255) / 256;

    // counting sort of edges by dst + inv_deg
    hipMemsetAsync(cursor, 0, (size_t)N * 4, stream);
    count_kernel<<<(E + 255) / 256, 256, 0, stream>>>(dst, cursor, E);
    invd_kernel<<<nb1, 256, 0, stream>>>(cursor, invd, N);
    scan1_kernel<<<nb1, 256, 0, stream>>>(cursor, bsum, N);
    scan2_kernel<<<1, 512, 0, stream>>>(bsum, nb1);
    scan3_kernel<<<nb1, 256, 0, stream>>>(cursor, bsum, rowptr, N, E);
    hipMemsetAsync(cursor, 0, (size_t)N * 4, stream);
    scatter_kernel<<<(E + 255) / 256, 256, 0, stream>>>(src, dst, w, rowptr, cursor, srcS, wS, E);

    // weight split + coefficient extract + embedding
    wsplit_kernel<<<4864, 256, 0, stream>>>(W1, W2, Wh1, W1hi, W1lo, W2hi, W2lo, Wh1hi, Wh1lo);
    extract_kernel<<<6, 256, 0, stream>>>(W1, ccAll);
    emb_split_kernel<<<N, 256, 0, stream>>>(gate_type, emb, hHi, hLo, N);

    const int gm = (N + 63) / 64;
    for (int l = 0; l < NLAYERS; ++l) {
        // t = h @ W1a^T  (bf16x3, out single bf16)
        mfma_gemm_kernel<256, false, false><<<gm, 256, 0, stream>>>(
            hHi, hLo, nullptr, W1hi + (size_t)l * 65536, W1lo + (size_t)l * 65536,
            nullptr, tBuf, nullptr, N);
        edge_agg_kernel<<<(N + 3) / 4, 256, 0, stream>>>(
            rowptr, srcS, wS, tBuf, ccAll + (size_t)l * 768, invd, hNBuf, N);
        // h = relu([h, hN] @ W2^T + b2)  (in-place: BN=256 full-width blocks)
        mfma_gemm_kernel<512, true, true><<<gm, 256, 0, stream>>>(
            hHi, hLo, hNBuf, W2hi + (size_t)l * 131072, W2lo + (size_t)l * 131072,
            b2 + (size_t)l * 256, hHi, hLo, N);
    }
    // head
    mfma_gemm_kernel<256, true, true><<<gm, 256, 0, stream>>>(
        hHi, hLo, nullptr, Wh1hi, Wh1lo, bh1, hHi, hLo, N);
    head_out_kernel<<<(N + 3) / 4, 256, 0, stream>>>(hHi, hLo, Wh2, bh2, out, N);
}